// Round 6
// baseline (3510.480 us; speedup 1.0000x reference)
//
#include <hip/hip_runtime.h>
#include <cstdint>
#include <cstddef>

#define DI __device__ __forceinline__

typedef __bf16 bf16x8 __attribute__((ext_vector_type(8)));
typedef float  f32x4  __attribute__((ext_vector_type(4)));
typedef unsigned short ushort_t;

constexpr int BATCH = 1024;
constexpr int HID   = 2048;
constexpr int IN    = 76;
constexpr int SENC  = 49;
constexpr int TDEC  = 25;
constexpr int KX    = 128;          // x padded to 128 cols
constexpr int KP    = KX + HID;     // 2176 packed K
constexpr int BK    = 128;          // K-step (one LDS tile)
constexpr int KTT   = KP / BK;      // 17 K-steps
constexpr int OSTR  = TDEC * IN;    // 1900 (row stride of decoder_inputs and d_out)

DI unsigned short f2bf(float f) {
  union { float f; unsigned u; } v; v.f = f;
  unsigned u = v.u;
  return (unsigned short)((u + 0x7fffu + ((u >> 16) & 1u)) >> 16);  // RTNE
}

DI float bf2f(unsigned short h) {
  union { unsigned u; float f; } v; v.u = ((unsigned)h) << 16;
  return v.f;
}

DI f32x4 mfma16(bf16x8 a, bf16x8 b, f32x4 c) {
  return __builtin_amdgcn_mfma_f32_16x16x32_bf16(a, b, c, 0, 0, 0);
}

DI void gload_lds16(const void* g, void* l) {
  __builtin_amdgcn_global_load_lds((const __attribute__((address_space(1))) void*)g,
                                   (__attribute__((address_space(3))) void*)l,
                                   16, 0, 0);
}

DI float sigmoidf_(float x) { return 1.0f / (1.0f + __expf(-x)); }
DI float tanhf_(float x)    { return 1.0f - 2.0f / (1.0f + __expf(2.0f * x)); }

// ---------------- packing kernels (run once per launch) ----------------

__global__ void pack_W(const float* __restrict__ Wih, const float* __restrict__ Whh,
                       ushort_t* __restrict__ Wp) {
  int idx = blockIdx.x * 256 + threadIdx.x;
  if (idx >= 6144 * KP) return;
  int n = idx / KP;
  int k = idx - n * KP;
  float v = 0.f;
  if (k < IN)        v = Wih[(size_t)n * IN + k];
  else if (k >= KX)  v = Whh[(size_t)n * HID + (k - KX)];
  Wp[idx] = f2bf(v);
}

__global__ void pack_xe(const float* __restrict__ enc, ushort_t* __restrict__ xe) {
  int idx = blockIdx.x * 256 + threadIdx.x;
  if (idx >= SENC * BATCH * KX) return;
  int t = idx >> 17;
  int rem = idx & 131071;
  int b = rem >> 7, k = rem & 127;
  float v = (k < IN) ? enc[(size_t)b * (SENC * IN) + t * IN + k] : 0.f;
  xe[idx] = f2bf(v);
}

__global__ void pack_xd0(const float* __restrict__ dec, ushort_t* __restrict__ xd) {
  int idx = blockIdx.x * 256 + threadIdx.x;
  if (idx >= BATCH * KX) return;
  int b = idx >> 7, k = idx & 127;
  float v = (k < IN) ? dec[(size_t)b * OSTR + k] : 0.f;
  xd[idx] = f2bf(v);
}

__global__ void pack_fc(const float* __restrict__ fcw, ushort_t* __restrict__ Wfc) {
  int idx = blockIdx.x * 256 + threadIdx.x;
  if (idx >= 80 * HID) return;
  int n = idx >> 11, k = idx & 2047;
  float v = (n < IN) ? fcw[(size_t)n * HID + k] : 0.f;
  Wfc[idx] = f2bf(v);
}

// ---------------- fused GRU step: B-only LDS (3-buffer), A direct from global ----------
// grid 256 (8 m x 32 n), block 512 (8 waves, 4m x 2n; wave tile 32 rows x 96 gate-cols)
// LDS traffic/iter = B only (192 KB) ~= MFMA wall; A frags (64 KB/iter) come straight
// from global, L1-served (per-slice working set ~20 KB). 3-buffer B pipeline staged
// 2 iters ahead; ONE counted s_waitcnt vmcnt(14) + ONE barrier per iter; no lgkm
// drains (each ds_read is consumed by an in-wave MFMA before the next barrier).
__global__ __launch_bounds__(512, 2) void gru_step_kernel(
    const ushort_t* __restrict__ x,    // [1024][128] bf16
    const ushort_t* __restrict__ hbp,  // [1024][2048] bf16 h_prev
    const ushort_t* __restrict__ Wp,   // [6144][2176] bf16
    const float*    __restrict__ b_ih,
    const float*    __restrict__ b_hh,
    ushort_t*       __restrict__ hbn)  // [1024][2048] bf16 h_new
{
  __shared__ ushort_t lds[3][192 * BK];   // B tiles only: 48 KB x 3 = 144 KB

  const int tid  = threadIdx.x;
  const int lane = tid & 63;
  const int wid  = tid >> 6;        // 0..7
  const int bid  = blockIdx.x;
  // XCD swizzle: n-group constant per XCD (bid%8) -> W panel reused from one L2
  const int n_grp = (bid & 7) + 8 * (bid >> 6);   // 0..31
  const int m_grp = (bid >> 3) & 7;               // 0..7
  const int row0  = m_grp * 128;
  const int col0  = n_grp * 64;
  const int wm = wid >> 1, wn = wid & 1;          // 4m x 2n

  const int l15 = lane & 15;
  const int lhi = lane >> 4;                       // 0..3

  const f32x4 Z4 = {0.f, 0.f, 0.f, 0.f};
  f32x4 accr[2][2], accz[2][2], accN[2][2], accin[2][2];
  #pragma unroll
  for (int a = 0; a < 2; ++a)
    #pragma unroll
    for (int b = 0; b < 2; ++b) { accr[a][b] = Z4; accz[a][b] = Z4; accN[a][b] = Z4; accin[a][b] = Z4; }

  // B staging: 48 chunks of 1 KB (4 rows x 128 cols each); source col-chunk
  // pre-XORed with (row&15) so the linear gload_lds dest holds the swizzled
  // layout (scheme verified in R4: absmax OK, 0 bank conflicts).
  auto stageB = [&](ushort_t* Lb, int kt) {
    const int wk0 = kt * BK;
    #pragma unroll
    for (int c = 0; c < 6; ++c) {                 // 6 chunks/wave
      const int chunk = wid * 6 + c;              // 0..47
      const int brow = chunk * 4 + lhi;           // 0..191 (gate*64 + col)
      const int gg = brow >> 6, wi = brow & 63;
      const int swz = ((l15 ^ (((chunk & 3) << 2) + lhi)) << 3);
      gload_lds16(Wp + (size_t)(gg * HID + col0 + wi) * KP + wk0 + swz,
                  Lb + chunk * 512);
    }
  };

  // B fragment reads (consumer-side XOR): ks 0..3 selects 32-k slice
  auto readB = [&](const ushort_t* Lb, int ks, bf16x8 bg[3][2]) {
    const int el = (((ks << 2) + lhi) ^ l15) << 3;
    #pragma unroll
    for (int g = 0; g < 3; ++g)
      #pragma unroll
      for (int fn = 0; fn < 2; ++fn)
        bg[g][fn] = *reinterpret_cast<const bf16x8*>(
            &Lb[(g * 64 + wn * 32 + fn * 16 + l15) * BK + el]);
  };

  // A fragments straight from global (16 rows x 64 B contiguous per frag)
  auto loadAx = [&](int ks, bf16x8 af[2]) {
    #pragma unroll
    for (int fm = 0; fm < 2; ++fm)
      af[fm] = *reinterpret_cast<const bf16x8*>(
          &x[(size_t)(row0 + wm * 32 + fm * 16 + l15) * KX + ks * 32 + lhi * 8]);
  };
  auto loadAh = [&](int kt, int ks, bf16x8 af[2]) {   // kt >= 1
    const int k = (kt - 1) * BK + ks * 32 + lhi * 8;
    #pragma unroll
    for (int fm = 0; fm < 2; ++fm)
      af[fm] = *reinterpret_cast<const bf16x8*>(
          &hbp[(size_t)(row0 + wm * 32 + fm * 16 + l15) * HID + k]);
  };

  auto burst = [&](bf16x8 af[2], bf16x8 bg[3][2]) {
    __builtin_amdgcn_s_setprio(1);
    #pragma unroll
    for (int fm = 0; fm < 2; ++fm)
      #pragma unroll
      for (int fn = 0; fn < 2; ++fn) {
        accr[fm][fn] = mfma16(af[fm], bg[0][fn], accr[fm][fn]);
        accz[fm][fn] = mfma16(af[fm], bg[1][fn], accz[fm][fn]);
        accN[fm][fn] = mfma16(af[fm], bg[2][fn], accN[fm][fn]);
      }
    __builtin_amdgcn_s_setprio(0);
  };

  bf16x8 aS0[2], aS1[2], aS2[2], aS3[2];
  bf16x8 bSa[3][2], bSb[3][2];

  // prologue: 2 B-tiles in flight, A slices of tile 0 in flight
  stageB(&lds[0][0], 0);
  stageB(&lds[1][0], 1);
  loadAx(0, aS0); loadAx(1, aS1); loadAx(2, aS2); loadAx(3, aS3);

  for (int kt = 0; kt < KTT; ++kt) {
    ushort_t* cur = &lds[kt % 3][0];
    if (kt + 2 < KTT) stageB(&lds[(kt + 2) % 3][0], kt + 2);
    // exactly 20 VMEM ops (6 B-stage + 8 A + 6 B-stage) separate buffer kt's
    // stage from this wait -> vmcnt(14) guarantees buffer kt landed while
    // keeping the newest stage (+ tail of A) in flight
    asm volatile("s_waitcnt vmcnt(14)" ::: "memory");
    __builtin_amdgcn_s_barrier();

    readB(cur, 0, bSa);
    readB(cur, 1, bSb);
    burst(aS0, bSa);                                // slice 0
    if (kt + 1 < KTT) loadAh(kt + 1, 0, aS0);
    readB(cur, 2, bSa);
    burst(aS1, bSb);                                // slice 1
    if (kt + 1 < KTT) loadAh(kt + 1, 1, aS1);
    readB(cur, 3, bSb);
    burst(aS2, bSa);                                // slice 2
    if (kt + 1 < KTT) loadAh(kt + 1, 2, aS2);
    burst(aS3, bSb);                                // slice 3
    if (kt + 1 < KTT) loadAh(kt + 1, 3, aS3);

    if (kt == 0) {   // tile 0 (k 0..127 = x) complete: capture i_n, restart for h_n
      #pragma unroll
      for (int a = 0; a < 2; ++a)
        #pragma unroll
        for (int b = 0; b < 2; ++b) { accin[a][b] = accN[a][b]; accN[a][b] = Z4; }
    }
  }

  // epilogue: gates + recurrence, bf16 state
  // C/D layout: col = lane&15, row = (lane>>4)*4 + q
  const int lqb = lhi * 4;
  #pragma unroll
  for (int fn = 0; fn < 2; ++fn) {
    const int j = col0 + wn * 32 + fn * 16 + l15;
    const float br  = b_ih[j] + b_hh[j];
    const float bz  = b_ih[HID + j] + b_hh[HID + j];
    const float bin = b_ih[2 * HID + j];
    const float bhn = b_hh[2 * HID + j];
    #pragma unroll
    for (int fm = 0; fm < 2; ++fm) {
      #pragma unroll
      for (int q = 0; q < 4; ++q) {
        const int row = row0 + wm * 32 + fm * 16 + lqb + q;
        const size_t off = (size_t)row * HID + j;
        const float hp = bf2f(hbp[off]);
        const float rr = sigmoidf_(accr[fm][fn][q] + br);
        const float zz = sigmoidf_(accz[fm][fn][q] + bz);
        const float nn = tanhf_(accin[fm][fn][q] + bin + rr * (accN[fm][fn][q] + bhn));
        const float hv = (1.0f - zz) * nn + zz * hp;
        hbn[off] = f2bf(hv);
      }
    }
  }
}

// ---------------- decoder fc: out = prev + h_new @ fc_w^T + fc_b; also emit next x (bf16) ----
__global__ __launch_bounds__(256) void fc_kernel(
    const ushort_t* __restrict__ hb,    // [1024][2048] bf16 h_new
    const ushort_t* __restrict__ Wfc,   // [80][2048] bf16
    const float*    __restrict__ fc_b,
    const float*    __restrict__ prev,  // row stride OSTR
    float*          __restrict__ outp,  // d_out + t*IN, row stride OSTR
    ushort_t*       __restrict__ xd)    // [1024][128] bf16 next input
{
  __shared__ float red[4][16][80];
  const int tid = threadIdx.x, lane = tid & 63, wid = tid >> 6;
  const int r0 = blockIdx.x * 16;
  const int lr = lane & 15, lk = (lane >> 4) * 8;
  const f32x4 Z4 = {0.f, 0.f, 0.f, 0.f};
  f32x4 acc[5];
  #pragma unroll
  for (int f = 0; f < 5; ++f) acc[f] = Z4;
  const int kbase = wid * 512;
  #pragma unroll
  for (int ks = 0; ks < 16; ++ks) {
    const int k = kbase + ks * 32 + lk;
    bf16x8 a = *reinterpret_cast<const bf16x8*>(&hb[(size_t)(r0 + lr) * HID + k]);
    #pragma unroll
    for (int f = 0; f < 5; ++f) {
      bf16x8 b = *reinterpret_cast<const bf16x8*>(&Wfc[(size_t)(f * 16 + lr) * HID + k]);
      acc[f] = mfma16(a, b, acc[f]);
    }
  }
  #pragma unroll
  for (int f = 0; f < 5; ++f)
    #pragma unroll
    for (int q = 0; q < 4; ++q)
      red[wid][(lane >> 4) * 4 + q][f * 16 + lr] = acc[f][q];
  __syncthreads();

  const int rowi = tid >> 4;          // 0..15
  const int j0   = (tid & 15) * 8;    // 0..120
  const int b_   = r0 + rowi;
  #pragma unroll
  for (int jj = 0; jj < 8; ++jj) {
    const int j = j0 + jj;
    float ov = 0.f;
    if (j < IN) {
      float s = red[0][rowi][j] + red[1][rowi][j] + red[2][rowi][j] + red[3][rowi][j];
      ov = prev[(size_t)b_ * OSTR + j] + fc_b[j] + s;
      outp[(size_t)b_ * OSTR + j] = ov;
    }
    xd[b_ * KX + j] = f2bf(j < IN ? ov : 0.f);
  }
}

// ---------------- host launch ----------------
extern "C" void kernel_launch(void* const* d_in, const int* in_sizes, int n_in,
                              void* d_out, int out_size, void* d_ws, size_t ws_size,
                              hipStream_t stream) {
  const float* enc = (const float*)d_in[0];
  const float* dec = (const float*)d_in[1];
  const float* Wih = (const float*)d_in[2];
  const float* Whh = (const float*)d_in[3];
  const float* bih = (const float*)d_in[4];
  const float* bhh = (const float*)d_in[5];
  const float* fcw = (const float*)d_in[6];
  const float* fcb = (const float*)d_in[7];
  float* out = (float*)d_out;

  char* ws = (char*)d_ws;
  ushort_t* Wp  = (ushort_t*)ws;  ws += (size_t)6144 * KP * 2;          // 26.7 MB
  ushort_t* xe  = (ushort_t*)ws;  ws += (size_t)SENC * BATCH * KX * 2;  // 12.8 MB
  ushort_t* xd  = (ushort_t*)ws;  ws += (size_t)BATCH * KX * 2;         // 256 KB
  ushort_t* Wfc = (ushort_t*)ws;  ws += (size_t)80 * HID * 2;           // 320 KB
  ushort_t* hb0 = (ushort_t*)ws;  ws += (size_t)BATCH * HID * 2;
  ushort_t* hb1 = (ushort_t*)ws;  ws += (size_t)BATCH * HID * 2;
  ushort_t* hbp[2] = {hb0, hb1};

  pack_W  <<<(6144 * KP + 255) / 256, 256, 0, stream>>>(Wih, Whh, Wp);
  pack_xe <<<(SENC * BATCH * KX + 255) / 256, 256, 0, stream>>>(enc, xe);
  pack_xd0<<<(BATCH * KX + 255) / 256, 256, 0, stream>>>(dec, xd);
  pack_fc <<<(80 * HID + 255) / 256, 256, 0, stream>>>(fcw, Wfc);
  hipMemsetAsync(hb0, 0, (size_t)BATCH * HID * 2, stream);

  for (int s = 0; s < SENC + TDEC; ++s) {
    const ushort_t* xsrc = (s < SENC) ? (xe + (size_t)s * BATCH * KX) : xd;
    gru_step_kernel<<<256, 512, 0, stream>>>(xsrc, hbp[s & 1], Wp, bih, bhh,
                                             hbp[(s + 1) & 1]);
    if (s >= SENC) {
      const int t = s - SENC;
      const float* prev = (t == 0) ? dec : (out + (size_t)(t - 1) * IN);
      fc_kernel<<<64, 256, 0, stream>>>(hbp[(s + 1) & 1], Wfc, fcb, prev,
                                        out + (size_t)t * IN, xd);
    }
  }
}

// Round 7
// 2691.211 us; speedup vs baseline: 1.3044x; 1.3044x over previous
//
#include <hip/hip_runtime.h>
#include <cstdint>
#include <cstddef>

#define DI __device__ __forceinline__

typedef __bf16 bf16x8 __attribute__((ext_vector_type(8)));
typedef float  f32x4  __attribute__((ext_vector_type(4)));
typedef unsigned short ushort_t;

constexpr int BATCH = 1024;
constexpr int HID   = 2048;
constexpr int IN    = 76;
constexpr int SENC  = 49;
constexpr int TDEC  = 25;
constexpr int KX    = 128;          // x padded to 128 cols
constexpr int KP    = KX + HID;     // 2176 packed K
constexpr int BK    = 64;           // K-step (one LDS tile)
constexpr int KTT   = KP / BK;      // 34 K-steps
constexpr int OSTR  = TDEC * IN;    // 1900 (row stride of decoder_inputs and d_out)

DI unsigned short f2bf(float f) {
  union { float f; unsigned u; } v; v.f = f;
  unsigned u = v.u;
  return (unsigned short)((u + 0x7fffu + ((u >> 16) & 1u)) >> 16);  // RTNE
}

DI float bf2f(unsigned short h) {
  union { unsigned u; float f; } v; v.u = ((unsigned)h) << 16;
  return v.f;
}

DI f32x4 mfma16(bf16x8 a, bf16x8 b, f32x4 c) {
  return __builtin_amdgcn_mfma_f32_16x16x32_bf16(a, b, c, 0, 0, 0);
}

DI void gload_lds16(const void* g, void* l) {
  __builtin_amdgcn_global_load_lds((const __attribute__((address_space(1))) void*)g,
                                   (__attribute__((address_space(3))) void*)l,
                                   16, 0, 0);
}

DI float sigmoidf_(float x) { return 1.0f / (1.0f + __expf(-x)); }
DI float tanhf_(float x)    { return 1.0f - 2.0f / (1.0f + __expf(2.0f * x)); }

// ---------------- packing kernels (run once per launch) ----------------

__global__ void pack_W(const float* __restrict__ Wih, const float* __restrict__ Whh,
                       ushort_t* __restrict__ Wp) {
  int idx = blockIdx.x * 256 + threadIdx.x;
  if (idx >= 6144 * KP) return;
  int n = idx / KP;
  int k = idx - n * KP;
  float v = 0.f;
  if (k < IN)        v = Wih[(size_t)n * IN + k];
  else if (k >= KX)  v = Whh[(size_t)n * HID + (k - KX)];
  Wp[idx] = f2bf(v);
}

__global__ void pack_xe(const float* __restrict__ enc, ushort_t* __restrict__ xe) {
  int idx = blockIdx.x * 256 + threadIdx.x;
  if (idx >= SENC * BATCH * KX) return;
  int t = idx >> 17;
  int rem = idx & 131071;
  int b = rem >> 7, k = rem & 127;
  float v = (k < IN) ? enc[(size_t)b * (SENC * IN) + t * IN + k] : 0.f;
  xe[idx] = f2bf(v);
}

__global__ void pack_xd0(const float* __restrict__ dec, ushort_t* __restrict__ xd) {
  int idx = blockIdx.x * 256 + threadIdx.x;
  if (idx >= BATCH * KX) return;
  int b = idx >> 7, k = idx & 127;
  float v = (k < IN) ? dec[(size_t)b * OSTR + k] : 0.f;
  xd[idx] = f2bf(v);
}

__global__ void pack_fc(const float* __restrict__ fcw, ushort_t* __restrict__ Wfc) {
  int idx = blockIdx.x * 256 + threadIdx.x;
  if (idx >= 80 * HID) return;
  int n = idx >> 11, k = idx & 2047;
  float v = (n < IN) ? fcw[(size_t)n * HID + k] : 0.f;
  Wfc[idx] = f2bf(v);
}

// ---------------- fused GRU step: 8 waves 2m x 4n (wave 64r x 48gc), 3-buf LDS ----------
// grid 256 (8 m x 32 n), block 512. Per wave per ks: 7 ds_read_b128 (4 A + 3 B) feeding
// 12 MFMA -> per-CU LDS wall 1318 cyc vs MFMA 931 per BK=64 iter (was 32 reads / 3072).
// 3-buffer LDS (120 KB), stage kt+2 at iter top, counted vmcnt(5) at iter bottom
// (newest stage stays in flight), ONE barrier per iter. R1-proven staging/swizzle.
__global__ __launch_bounds__(512, 2) void gru_step_kernel(
    const ushort_t* __restrict__ x,    // [1024][128] bf16
    const ushort_t* __restrict__ hbp,  // [1024][2048] bf16 h_prev
    const ushort_t* __restrict__ Wp,   // [6144][2176] bf16
    const float*    __restrict__ b_ih,
    const float*    __restrict__ b_hh,
    ushort_t*       __restrict__ hbn)  // [1024][2048] bf16 h_new
{
  __shared__ ushort_t lds[3][(128 + 192) * BK];   // A 128x64 + B 192x64 = 40 KB x 3

  const int tid  = threadIdx.x;
  const int lane = tid & 63;
  const int wid  = tid >> 6;        // 0..7
  const int bid  = blockIdx.x;
  // XCD swizzle: n-group constant per XCD (bid%8) -> W panel reused from one L2
  const int n_grp = (bid & 7) + 8 * (bid >> 6);   // 0..31
  const int m_grp = (bid >> 3) & 7;               // 0..7
  const int row0  = m_grp * 128;
  const int col0  = n_grp * 64;
  const int wm = wid >> 2;          // 0..1 : 64-row half
  const int wn = wid & 3;           // 0..3 : 16-col quarter (per gate)

  const f32x4 Z4 = {0.f, 0.f, 0.f, 0.f};
  f32x4 accr[4], accz[4], accN[4], accin[4];
  #pragma unroll
  for (int a = 0; a < 4; ++a) { accr[a] = Z4; accz[a] = Z4; accN[a] = Z4; accin[a] = Z4; }

  // staging constants (R1-proven): chunk = 8 rows x 64 cols (1 KB); row = lane>>3;
  // source 16B-group pre-XORed with (row&7) so linear LDS dest holds swizzled layout
  const int srow  = lane >> 3;
  const int swcol = (((lane & 7) ^ (srow & 7)) << 3);   // elements

  // fragment-read constants (consumer-side XOR, R1-proven)
  const int lr  = lane & 15;
  const int bc  = (lane >> 4) * 16;                       // byte col, pre-swizzle
  const int ksw0 = ((bc)      ^ ((lane & 7) << 4)) >> 1;  // element offsets
  const int ksw1 = ((64 + bc) ^ ((lane & 7) << 4)) >> 1;

  auto stage = [&](int buf, int kt) {
    const ushort_t* asrc; int astr, ak0;
    if (kt < 2) { asrc = x;   astr = KX;  ak0 = kt * BK; }
    else        { asrc = hbp; astr = HID; ak0 = (kt - 2) * BK; }
    ushort_t* Lb = &lds[buf][0];
    #pragma unroll
    for (int c = 0; c < 2; ++c) {                 // A: 2 chunks/wave (16 total)
      const int chunk = wid * 2 + c;
      const ushort_t* g = asrc + (size_t)(row0 + chunk * 8 + srow) * astr + ak0 + swcol;
      gload_lds16(g, Lb + chunk * 512);
    }
    const int wk0 = kt * BK;
    #pragma unroll
    for (int c = 0; c < 3; ++c) {                 // B: 3 chunks/wave (24 total)
      const int chunk = wid * 3 + c;
      const int brow = chunk * 8 + srow;          // 0..191 (gate*64 + col)
      const int gg = brow >> 6, wi = brow & 63;
      const ushort_t* g = Wp + (size_t)(gg * HID + col0 + wi) * KP + wk0 + swcol;
      gload_lds16(g, Lb + 128 * BK + chunk * 512);
    }
  };

  auto readFrags = [&](const ushort_t* base, int ko, bf16x8 af[4], bf16x8 bg[3]) {
    #pragma unroll
    for (int fm = 0; fm < 4; ++fm)
      af[fm] = *reinterpret_cast<const bf16x8*>(&base[(wm * 64 + fm * 16 + lr) * BK + ko]);
    #pragma unroll
    for (int g = 0; g < 3; ++g)
      bg[g] = *reinterpret_cast<const bf16x8*>(
          &base[128 * BK + (g * 64 + wn * 16 + lr) * BK + ko]);
  };

  auto burst = [&](bf16x8 af[4], bf16x8 bg[3]) {
    __builtin_amdgcn_s_setprio(1);
    #pragma unroll
    for (int fm = 0; fm < 4; ++fm) {
      accr[fm] = mfma16(af[fm], bg[0], accr[fm]);
      accz[fm] = mfma16(af[fm], bg[1], accz[fm]);
      accN[fm] = mfma16(af[fm], bg[2], accN[fm]);
    }
    __builtin_amdgcn_s_setprio(0);
  };

  bf16x8 afA[4], bgA[3];   // ks0 set
  bf16x8 afB[4], bgB[3];   // ks1 set

  // prologue: tiles 0,1 staged; tile 0 landed (wait all-but-newest-5)
  stage(0, 0);
  stage(1, 1);
  asm volatile("s_waitcnt vmcnt(5)" ::: "memory");
  __builtin_amdgcn_s_barrier();

  for (int kt = 0; kt < KTT; ++kt) {
    const ushort_t* base = &lds[kt % 3][0];
    readFrags(base, ksw0, afA, bgA);
    if (kt + 2 < KTT) stage((kt + 2) % 3, kt + 2);   // WAR-safe: buf read in iter kt-1, barrier since
    readFrags(base, ksw1, afB, bgB);                 // in flight under burst A
    burst(afA, bgA);
    burst(afB, bgB);

    if (kt == 1) {   // k 0..127 (= x tiles) done: capture i_n, restart for h_n
      #pragma unroll
      for (int a = 0; a < 4; ++a) { accin[a] = accN[a]; accN[a] = Z4; }
    }

    if (kt + 1 < KTT) {
      if (kt + 2 < KTT) { asm volatile("s_waitcnt vmcnt(5)" ::: "memory"); }  // kt+1 landed, kt+2 in flight
      else              { asm volatile("s_waitcnt vmcnt(0)" ::: "memory"); }
      __builtin_amdgcn_s_barrier();
    }
  }

  // epilogue: gates + recurrence, bf16 state
  // C/D layout: col = lane&15, row = (lane>>4)*4 + q
  const int lqb = (lane >> 4) * 4;
  const int j = col0 + wn * 16 + lr;
  const float br  = b_ih[j] + b_hh[j];
  const float bz  = b_ih[HID + j] + b_hh[HID + j];
  const float bin = b_ih[2 * HID + j];
  const float bhn = b_hh[2 * HID + j];
  #pragma unroll
  for (int fm = 0; fm < 4; ++fm) {
    #pragma unroll
    for (int q = 0; q < 4; ++q) {
      const int row = row0 + wm * 64 + fm * 16 + lqb + q;
      const size_t off = (size_t)row * HID + j;
      const float hp = bf2f(hbp[off]);
      const float rr = sigmoidf_(accr[fm][q] + br);
      const float zz = sigmoidf_(accz[fm][q] + bz);
      const float nn = tanhf_(accin[fm][q] + bin + rr * (accN[fm][q] + bhn));
      const float hv = (1.0f - zz) * nn + zz * hp;
      hbn[off] = f2bf(hv);
    }
  }
}

// ---------------- decoder fc: out = prev + h_new @ fc_w^T + fc_b; also emit next x (bf16) ----
__global__ __launch_bounds__(256) void fc_kernel(
    const ushort_t* __restrict__ hb,    // [1024][2048] bf16 h_new
    const ushort_t* __restrict__ Wfc,   // [80][2048] bf16
    const float*    __restrict__ fc_b,
    const float*    __restrict__ prev,  // row stride OSTR
    float*          __restrict__ outp,  // d_out + t*IN, row stride OSTR
    ushort_t*       __restrict__ xd)    // [1024][128] bf16 next input
{
  __shared__ float red[4][16][80];
  const int tid = threadIdx.x, lane = tid & 63, wid = tid >> 6;
  const int r0 = blockIdx.x * 16;
  const int lr = lane & 15, lk = (lane >> 4) * 8;
  const f32x4 Z4 = {0.f, 0.f, 0.f, 0.f};
  f32x4 acc[5];
  #pragma unroll
  for (int f = 0; f < 5; ++f) acc[f] = Z4;
  const int kbase = wid * 512;
  #pragma unroll
  for (int ks = 0; ks < 16; ++ks) {
    const int k = kbase + ks * 32 + lk;
    bf16x8 a = *reinterpret_cast<const bf16x8*>(&hb[(size_t)(r0 + lr) * HID + k]);
    #pragma unroll
    for (int f = 0; f < 5; ++f) {
      bf16x8 b = *reinterpret_cast<const bf16x8*>(&Wfc[(size_t)(f * 16 + lr) * HID + k]);
      acc[f] = mfma16(a, b, acc[f]);
    }
  }
  #pragma unroll
  for (int f = 0; f < 5; ++f)
    #pragma unroll
    for (int q = 0; q < 4; ++q)
      red[wid][(lane >> 4) * 4 + q][f * 16 + lr] = acc[f][q];
  __syncthreads();

  const int rowi = tid >> 4;          // 0..15
  const int j0   = (tid & 15) * 8;    // 0..120
  const int b_   = r0 + rowi;
  #pragma unroll
  for (int jj = 0; jj < 8; ++jj) {
    const int j = j0 + jj;
    float ov = 0.f;
    if (j < IN) {
      float s = red[0][rowi][j] + red[1][rowi][j] + red[2][rowi][j] + red[3][rowi][j];
      ov = prev[(size_t)b_ * OSTR + j] + fc_b[j] + s;
      outp[(size_t)b_ * OSTR + j] = ov;
    }
    xd[b_ * KX + j] = f2bf(j < IN ? ov : 0.f);
  }
}

// ---------------- host launch ----------------
extern "C" void kernel_launch(void* const* d_in, const int* in_sizes, int n_in,
                              void* d_out, int out_size, void* d_ws, size_t ws_size,
                              hipStream_t stream) {
  const float* enc = (const float*)d_in[0];
  const float* dec = (const float*)d_in[1];
  const float* Wih = (const float*)d_in[2];
  const float* Whh = (const float*)d_in[3];
  const float* bih = (const float*)d_in[4];
  const float* bhh = (const float*)d_in[5];
  const float* fcw = (const float*)d_in[6];
  const float* fcb = (const float*)d_in[7];
  float* out = (float*)d_out;

  char* ws = (char*)d_ws;
  ushort_t* Wp  = (ushort_t*)ws;  ws += (size_t)6144 * KP * 2;          // 26.7 MB
  ushort_t* xe  = (ushort_t*)ws;  ws += (size_t)SENC * BATCH * KX * 2;  // 12.8 MB
  ushort_t* xd  = (ushort_t*)ws;  ws += (size_t)BATCH * KX * 2;         // 256 KB
  ushort_t* Wfc = (ushort_t*)ws;  ws += (size_t)80 * HID * 2;           // 320 KB
  ushort_t* hb0 = (ushort_t*)ws;  ws += (size_t)BATCH * HID * 2;
  ushort_t* hb1 = (ushort_t*)ws;  ws += (size_t)BATCH * HID * 2;
  ushort_t* hbp[2] = {hb0, hb1};

  pack_W  <<<(6144 * KP + 255) / 256, 256, 0, stream>>>(Wih, Whh, Wp);
  pack_xe <<<(SENC * BATCH * KX + 255) / 256, 256, 0, stream>>>(enc, xe);
  pack_xd0<<<(BATCH * KX + 255) / 256, 256, 0, stream>>>(dec, xd);
  pack_fc <<<(80 * HID + 255) / 256, 256, 0, stream>>>(fcw, Wfc);
  hipMemsetAsync(hb0, 0, (size_t)BATCH * HID * 2, stream);

  for (int s = 0; s < SENC + TDEC; ++s) {
    const ushort_t* xsrc = (s < SENC) ? (xe + (size_t)s * BATCH * KX) : xd;
    gru_step_kernel<<<256, 512, 0, stream>>>(xsrc, hbp[s & 1], Wp, bih, bhh,
                                             hbp[(s + 1) & 1]);
    if (s >= SENC) {
      const int t = s - SENC;
      const float* prev = (t == 0) ? dec : (out + (size_t)(t - 1) * IN);
      fc_kernel<<<64, 256, 0, stream>>>(hbp[(s + 1) & 1], Wfc, fcb, prev,
                                        out + (size_t)t * IN, xd);
    }
  }
}

// Round 9
// 2583.069 us; speedup vs baseline: 1.3590x; 1.0419x over previous
//
#include <hip/hip_runtime.h>
#include <cstdint>
#include <cstddef>

#define DI __device__ __forceinline__

typedef __bf16 bf16x8 __attribute__((ext_vector_type(8)));
typedef float  f32x4  __attribute__((ext_vector_type(4)));
typedef unsigned short ushort_t;

constexpr int BATCH = 1024;
constexpr int HID   = 2048;
constexpr int IN    = 76;
constexpr int SENC  = 49;
constexpr int TDEC  = 25;
constexpr int KX    = 128;          // x padded to 128 cols
constexpr int KP    = KX + HID;     // 2176 packed K
constexpr int BK    = 64;           // K-step (one LDS tile)
constexpr int KTT   = KP / BK;      // 34 K-steps
constexpr int OSTR  = TDEC * IN;    // 1900 (row stride of decoder_inputs and d_out)

DI unsigned short f2bf(float f) {
  union { float f; unsigned u; } v; v.f = f;
  unsigned u = v.u;
  return (unsigned short)((u + 0x7fffu + ((u >> 16) & 1u)) >> 16);  // RTNE
}

DI float bf2f(unsigned short h) {
  union { unsigned u; float f; } v; v.u = ((unsigned)h) << 16;
  return v.f;
}

DI f32x4 mfma16(bf16x8 a, bf16x8 b, f32x4 c) {
  return __builtin_amdgcn_mfma_f32_16x16x32_bf16(a, b, c, 0, 0, 0);
}

DI void gload_lds16(const void* g, void* l) {
  __builtin_amdgcn_global_load_lds((const __attribute__((address_space(1))) void*)g,
                                   (__attribute__((address_space(3))) void*)l,
                                   16, 0, 0);
}

DI float sigmoidf_(float x) { return 1.0f / (1.0f + __expf(-x)); }
DI float tanhf_(float x)    { return 1.0f - 2.0f / (1.0f + __expf(2.0f * x)); }

// ---------------- packing kernels (run once per launch) ----------------

__global__ void pack_W(const float* __restrict__ Wih, const float* __restrict__ Whh,
                       ushort_t* __restrict__ Wp) {
  int idx = blockIdx.x * 256 + threadIdx.x;
  if (idx >= 6144 * KP) return;
  int n = idx / KP;
  int k = idx - n * KP;
  float v = 0.f;
  if (k < IN)        v = Wih[(size_t)n * IN + k];
  else if (k >= KX)  v = Whh[(size_t)n * HID + (k - KX)];
  Wp[idx] = f2bf(v);
}

__global__ void pack_xe(const float* __restrict__ enc, ushort_t* __restrict__ xe) {
  int idx = blockIdx.x * 256 + threadIdx.x;
  if (idx >= SENC * BATCH * KX) return;
  int t = idx >> 17;
  int rem = idx & 131071;
  int b = rem >> 7, k = rem & 127;
  float v = (k < IN) ? enc[(size_t)b * (SENC * IN) + t * IN + k] : 0.f;
  xe[idx] = f2bf(v);
}

__global__ void pack_xd0(const float* __restrict__ dec, ushort_t* __restrict__ xd) {
  int idx = blockIdx.x * 256 + threadIdx.x;
  if (idx >= BATCH * KX) return;
  int b = idx >> 7, k = idx & 127;
  float v = (k < IN) ? dec[(size_t)b * OSTR + k] : 0.f;
  xd[idx] = f2bf(v);
}

__global__ void pack_fc(const float* __restrict__ fcw, ushort_t* __restrict__ Wfc) {
  int idx = blockIdx.x * 256 + threadIdx.x;
  if (idx >= 80 * HID) return;
  int n = idx >> 11, k = idx & 2047;
  float v = (n < IN) ? fcw[(size_t)n * HID + k] : 0.f;
  Wfc[idx] = f2bf(v);
}

// ---------------- fused GRU step: 2 blocks/CU for cross-block stall filling ----------
// grid 512 (8 m x 64 n), block 256 (4 waves, 2m x 2n; wave 64 rows x 48 gate-cols).
// Per-block tile 128 rows x 32 n-cols; B = 96 Wp rows. LDS 2 x 28 KB = 56 KB/block ->
// TWO independent blocks per CU: when one block sits in its vmcnt+barrier drain, the
// other block's waves feed the MFMA pipe (m114 cross-wave overlap, phase-decoupled).
// R8 bug fixed: A = 16 chunks total (4/wave), not 32 — chunks 16..31 were clobbering B.
__global__ __launch_bounds__(256, 2) void gru_step_kernel(
    const ushort_t* __restrict__ x,    // [1024][128] bf16
    const ushort_t* __restrict__ hbp,  // [1024][2048] bf16 h_prev
    const ushort_t* __restrict__ Wp,   // [6144][2176] bf16
    const float*    __restrict__ b_ih,
    const float*    __restrict__ b_hh,
    ushort_t*       __restrict__ hbn)  // [1024][2048] bf16 h_new
{
  __shared__ ushort_t lds[2][(128 + 96) * BK];   // A 128x64 + B 96x64 = 28 KB x 2

  const int tid  = threadIdx.x;
  const int lane = tid & 63;
  const int wid  = tid >> 6;        // 0..3
  const int bid  = blockIdx.x;
  // XCD mapping: bid%8 -> XCD (round-robin dispatch); same-XCD blocks share 8 W panels
  // (8 n_grps x 96 rows x 4.25 KB = 3.3 MB < 4 MB per-XCD L2)
  const int xcd   = bid & 7;
  const int idx   = bid >> 3;                     // 0..63
  const int m_grp = idx & 7;                      // 0..7
  const int n_grp = xcd + 8 * (idx >> 3);         // 0..63
  const int row0  = m_grp * 128;
  const int col0  = n_grp * 32;
  const int wm = wid >> 1;          // 0..1 : 64-row half
  const int wn = wid & 1;           // 0..1 : 16-col half (per gate)

  const f32x4 Z4 = {0.f, 0.f, 0.f, 0.f};
  f32x4 accr[4], accz[4], accN[4], accin[4];
  #pragma unroll
  for (int a = 0; a < 4; ++a) { accr[a] = Z4; accz[a] = Z4; accN[a] = Z4; accin[a] = Z4; }

  // staging constants (R1/R4-proven): chunk = 8 rows x 64 cols (1 KB); row = lane>>3;
  // source 16B-group pre-XORed with (row&7) so linear LDS dest holds swizzled layout
  const int srow  = lane >> 3;
  const int swcol = (((lane & 7) ^ (srow & 7)) << 3);   // elements

  // fragment-read constants (consumer-side XOR, proven)
  const int lr  = lane & 15;
  const int bc  = (lane >> 4) * 16;                       // byte col, pre-swizzle
  const int ksw0 = ((bc)      ^ ((lane & 7) << 4)) >> 1;  // element offsets
  const int ksw1 = ((64 + bc) ^ ((lane & 7) << 4)) >> 1;

  auto stage = [&](int buf, int kt) {
    const ushort_t* asrc; int astr, ak0;
    if (kt < 2) { asrc = x;   astr = KX;  ak0 = kt * BK; }
    else        { asrc = hbp; astr = HID; ak0 = (kt - 2) * BK; }
    ushort_t* Lb = &lds[buf][0];
    #pragma unroll
    for (int c = 0; c < 4; ++c) {                 // A: 4 chunks/wave (16 total = 128 rows)
      const int chunk = wid * 4 + c;              // 0..15
      const ushort_t* g = asrc + (size_t)(row0 + chunk * 8 + srow) * astr + ak0 + swcol;
      gload_lds16(g, Lb + chunk * 512);
    }
    const int wk0 = kt * BK;
    #pragma unroll
    for (int c = 0; c < 3; ++c) {                 // B: 3 chunks/wave (12 total = 96 rows)
      const int chunk = wid * 3 + c;              // 0..11
      const int brow = chunk * 8 + srow;          // 0..95 (gate*32 + col)
      const int gg = brow >> 5, wi = brow & 31;
      const ushort_t* g = Wp + (size_t)(gg * HID + col0 + wi) * KP + wk0 + swcol;
      gload_lds16(g, Lb + 128 * BK + chunk * 512);
    }
  };

  auto readFrags = [&](const ushort_t* base, int ko, bf16x8 af[4], bf16x8 bg[3]) {
    #pragma unroll
    for (int fm = 0; fm < 4; ++fm)
      af[fm] = *reinterpret_cast<const bf16x8*>(&base[(wm * 64 + fm * 16 + lr) * BK + ko]);
    #pragma unroll
    for (int g = 0; g < 3; ++g)
      bg[g] = *reinterpret_cast<const bf16x8*>(
          &base[128 * BK + (g * 32 + wn * 16 + lr) * BK + ko]);
  };

  auto burst = [&](bf16x8 af[4], bf16x8 bg[3]) {
    __builtin_amdgcn_s_setprio(1);
    #pragma unroll
    for (int fm = 0; fm < 4; ++fm) {
      accr[fm] = mfma16(af[fm], bg[0], accr[fm]);
      accz[fm] = mfma16(af[fm], bg[1], accz[fm]);
      accN[fm] = mfma16(af[fm], bg[2], accN[fm]);
    }
    __builtin_amdgcn_s_setprio(0);
  };

  bf16x8 afA[4], bgA[3];   // ks0 set
  bf16x8 afB[4], bgB[3];   // ks1 set

  // prologue: tile 0 staged and landed
  stage(0, 0);
  asm volatile("s_waitcnt vmcnt(0)" ::: "memory");
  __builtin_amdgcn_s_barrier();

  for (int kt = 0; kt < KTT; ++kt) {
    const ushort_t* base = &lds[kt & 1][0];
    if (kt + 1 < KTT) stage((kt + 1) & 1, kt + 1);   // into the half freed by iter kt-1
    readFrags(base, ksw0, afA, bgA);
    readFrags(base, ksw1, afB, bgB);                 // in flight under burst A
    burst(afA, bgA);
    burst(afB, bgB);

    if (kt == 1) {   // k 0..127 (= x tiles) done: capture i_n, restart for h_n
      #pragma unroll
      for (int a = 0; a < 4; ++a) { accin[a] = accN[a]; accN[a] = Z4; }
    }

    if (kt + 1 < KTT) {
      asm volatile("s_waitcnt vmcnt(0)" ::: "memory");  // tile kt+1 landed
      __builtin_amdgcn_s_barrier();
    }
  }

  // epilogue: gates + recurrence, bf16 state
  // C/D layout: col = lane&15, row = (lane>>4)*4 + q
  const int lqb = (lane >> 4) * 4;
  const int j = col0 + wn * 16 + lr;
  const float br  = b_ih[j] + b_hh[j];
  const float bz  = b_ih[HID + j] + b_hh[HID + j];
  const float bin = b_ih[2 * HID + j];
  const float bhn = b_hh[2 * HID + j];
  #pragma unroll
  for (int fm = 0; fm < 4; ++fm) {
    #pragma unroll
    for (int q = 0; q < 4; ++q) {
      const int row = row0 + wm * 64 + fm * 16 + lqb + q;
      const size_t off = (size_t)row * HID + j;
      const float hp = bf2f(hbp[off]);
      const float rr = sigmoidf_(accr[fm][q] + br);
      const float zz = sigmoidf_(accz[fm][q] + bz);
      const float nn = tanhf_(accin[fm][q] + bin + rr * (accN[fm][q] + bhn));
      const float hv = (1.0f - zz) * nn + zz * hp;
      hbn[off] = f2bf(hv);
    }
  }
}

// ---------------- decoder fc: out = prev + h_new @ fc_w^T + fc_b; also emit next x (bf16) ----
__global__ __launch_bounds__(256) void fc_kernel(
    const ushort_t* __restrict__ hb,    // [1024][2048] bf16 h_new
    const ushort_t* __restrict__ Wfc,   // [80][2048] bf16
    const float*    __restrict__ fc_b,
    const float*    __restrict__ prev,  // row stride OSTR
    float*          __restrict__ outp,  // d_out + t*IN, row stride OSTR
    ushort_t*       __restrict__ xd)    // [1024][128] bf16 next input
{
  __shared__ float red[4][16][80];
  const int tid = threadIdx.x, lane = tid & 63, wid = tid >> 6;
  const int r0 = blockIdx.x * 16;
  const int lr = lane & 15, lk = (lane >> 4) * 8;
  const f32x4 Z4 = {0.f, 0.f, 0.f, 0.f};
  f32x4 acc[5];
  #pragma unroll
  for (int f = 0; f < 5; ++f) acc[f] = Z4;
  const int kbase = wid * 512;
  #pragma unroll
  for (int ks = 0; ks < 16; ++ks) {
    const int k = kbase + ks * 32 + lk;
    bf16x8 a = *reinterpret_cast<const bf16x8*>(&hb[(size_t)(r0 + lr) * HID + k]);
    #pragma unroll
    for (int f = 0; f < 5; ++f) {
      bf16x8 b = *reinterpret_cast<const bf16x8*>(&Wfc[(size_t)(f * 16 + lr) * HID + k]);
      acc[f] = mfma16(a, b, acc[f]);
    }
  }
  #pragma unroll
  for (int f = 0; f < 5; ++f)
    #pragma unroll
    for (int q = 0; q < 4; ++q)
      red[wid][(lane >> 4) * 4 + q][f * 16 + lr] = acc[f][q];
  __syncthreads();

  const int rowi = tid >> 4;          // 0..15
  const int j0   = (tid & 15) * 8;    // 0..120
  const int b_   = r0 + rowi;
  #pragma unroll
  for (int jj = 0; jj < 8; ++jj) {
    const int j = j0 + jj;
    float ov = 0.f;
    if (j < IN) {
      float s = red[0][rowi][j] + red[1][rowi][j] + red[2][rowi][j] + red[3][rowi][j];
      ov = prev[(size_t)b_ * OSTR + j] + fc_b[j] + s;
      outp[(size_t)b_ * OSTR + j] = ov;
    }
    xd[b_ * KX + j] = f2bf(j < IN ? ov : 0.f);
  }
}

// ---------------- host launch ----------------
extern "C" void kernel_launch(void* const* d_in, const int* in_sizes, int n_in,
                              void* d_out, int out_size, void* d_ws, size_t ws_size,
                              hipStream_t stream) {
  const float* enc = (const float*)d_in[0];
  const float* dec = (const float*)d_in[1];
  const float* Wih = (const float*)d_in[2];
  const float* Whh = (const float*)d_in[3];
  const float* bih = (const float*)d_in[4];
  const float* bhh = (const float*)d_in[5];
  const float* fcw = (const float*)d_in[6];
  const float* fcb = (const float*)d_in[7];
  float* out = (float*)d_out;

  char* ws = (char*)d_ws;
  ushort_t* Wp  = (ushort_t*)ws;  ws += (size_t)6144 * KP * 2;          // 26.7 MB
  ushort_t* xe  = (ushort_t*)ws;  ws += (size_t)SENC * BATCH * KX * 2;  // 12.8 MB
  ushort_t* xd  = (ushort_t*)ws;  ws += (size_t)BATCH * KX * 2;         // 256 KB
  ushort_t* Wfc = (ushort_t*)ws;  ws += (size_t)80 * HID * 2;           // 320 KB
  ushort_t* hb0 = (ushort_t*)ws;  ws += (size_t)BATCH * HID * 2;
  ushort_t* hb1 = (ushort_t*)ws;  ws += (size_t)BATCH * HID * 2;
  ushort_t* hbp[2] = {hb0, hb1};

  pack_W  <<<(6144 * KP + 255) / 256, 256, 0, stream>>>(Wih, Whh, Wp);
  pack_xe <<<(SENC * BATCH * KX + 255) / 256, 256, 0, stream>>>(enc, xe);
  pack_xd0<<<(BATCH * KX + 255) / 256, 256, 0, stream>>>(dec, xd);
  pack_fc <<<(80 * HID + 255) / 256, 256, 0, stream>>>(fcw, Wfc);
  hipMemsetAsync(hb0, 0, (size_t)BATCH * HID * 2, stream);

  for (int s = 0; s < SENC + TDEC; ++s) {
    const ushort_t* xsrc = (s < SENC) ? (xe + (size_t)s * BATCH * KX) : xd;
    gru_step_kernel<<<512, 256, 0, stream>>>(xsrc, hbp[s & 1], Wp, bih, bhh,
                                             hbp[(s + 1) & 1]);
    if (s >= SENC) {
      const int t = s - SENC;
      const float* prev = (t == 0) ? dec : (out + (size_t)(t - 1) * IN);
      fc_kernel<<<64, 256, 0, stream>>>(hbp[(s + 1) & 1], Wfc, fcb, prev,
                                        out + (size_t)t * IN, xd);
    }
  }
}